// Round 4
// baseline (422.458 us; speedup 1.0000x reference)
//
#include <hip/hip_runtime.h>

typedef __attribute__((ext_vector_type(8))) _Float16 f16x8;
typedef __attribute__((ext_vector_type(4))) _Float16 f16x4;
typedef __attribute__((ext_vector_type(4))) float f32x4;

#define N_B 64
#define T_F 300
#define TB 4
#define NT (T_F/TB)

// ws byte offsets
#define AY_OFF  0        // f16 [4][128][8]    y-GEMM A operand, K-chunked
#define WH_OFF  8192     // f16 [96][32]       folded mlp weight; k=0..14: Wh[(s-1)*3+c], k=15: folded bias
#define OWC_OFF 14336    // f16 [6][12][96][8] folded out weight, chunked
#define BP_OFF  124928   // float[96]          (unused by main now; kept for layout stability)
#define OB_OFF  125312   // float[96]
#define W2_OFF  125696   // float[96][32][4]   diag weights W2[o][v][c] (c<3 used)

__device__ __constant__ int EDGES[24][2] = {
  {1,2},{2,21},{3,21},{4,3},{5,21},{6,5},{7,6},{8,7},{9,21},{10,9},{11,10},{12,11},
  {13,1},{14,13},{15,14},{16,15},{17,1},{18,17},{19,18},{20,19},{22,23},{23,8},{24,25},{25,12}
};

__global__ void setup_kernel(const float* __restrict__ mlp_w, const float* __restrict__ mlp_b,
    const float* __restrict__ g1, const float* __restrict__ be1,
    const float* __restrict__ mu1, const float* __restrict__ va1,
    const float* __restrict__ out_w, const float* __restrict__ out_b,
    const float* __restrict__ g2, const float* __restrict__ be2,
    const float* __restrict__ mu2, const float* __restrict__ va2,
    char* __restrict__ wsb) {
  _Float16* Ay  = (_Float16*)(wsb + AY_OFF);
  _Float16* Wh  = (_Float16*)(wsb + WH_OFF);
  _Float16* OWc = (_Float16*)(wsb + OWC_OFF);
  float* bp  = (float*)(wsb + BP_OFF);
  float* ob  = (float*)(wsb + OB_OFF);
  float* W2  = (float*)(wsb + W2_OFF);
  int tid = threadIdx.x;

  if (blockIdx.x == 0) {
    // A_large = J5 (x) B with B = A+I  =>  scale s reduces to 25-node graph:
    //   s=0: A_s = I;  s=1: M = J(x)B;  s>=2: M = J(x)(R_s\R_{s-1}) + I.
    __shared__ unsigned int Rk[6][25];
    __shared__ unsigned int Gs[6][25];
    __shared__ float dv[6][25];
    if (tid < 25) {
      unsigned int m = 1u << tid;
      for (int e = 0; e < 24; ++e) {
        int a = EDGES[e][0]-1, b = EDGES[e][1]-1;
        if (a == tid) m |= 1u<<b;
        if (b == tid) m |= 1u<<a;
      }
      Gs[1][tid] = m;   // B masks (incl. self)
      Rk[1][tid] = m;
    }
    __syncthreads();
    for (int k = 2; k <= 5; ++k) {
      if (tid < 25) {
        unsigned int p = Rk[k-1][tid], nm = p;
        for (int j = 0; j < 25; ++j) if ((p>>j)&1u) nm |= Gs[1][j];
        Rk[k][tid] = nm;
      }
      __syncthreads();
    }
    if (tid < 25) {
      for (int s = 1; s <= 5; ++s) {
        unsigned int g = (s==1) ? Gs[1][tid] : (Rk[s][tid] & ~Rk[s-1][tid]);
        if (s >= 2) Gs[s][tid] = g;
        int d = 5*__popc(g) + ((s>=2)?1:0);
        dv[s][tid] = (d>0) ? (float)(1.0/sqrt((double)d)) : 0.0f;
      }
    }
    __syncthreads();
    // Ay: [kc=0..3][row=0..127][j=0..7], row=(s-1)*25+v for s=1..5, i = kc*8+j
    for (int idx = tid; idx < 4096; idx += 256) {
      int kc = idx >> 10, row = (idx>>3)&127, j = idx&7;
      int i = kc*8 + j;
      float val = 0.f;
      if (row < 125 && i < 25) {
        int s = 1 + row/25, v = row - (s-1)*25;
        if ((Gs[s][v] >> i) & 1u) val = dv[s][v]*dv[s][i];
      }
      Ay[idx] = (_Float16)val;
    }
    // W2[o][v][c]: s=0 identity + s>=2 diagonal corrections, BN-folded
    for (int i = tid; i < 96*32; i += 256) {
      int o = i>>5, v = i&31;
      f32x4 w4 = {0.f,0.f,0.f,0.f};
      if (v < 25) {
        float inv = g1[o] / sqrtf(va1[o] + 1e-5f);
        #pragma unroll
        for (int c = 0; c < 3; ++c) {
          float acc = mlp_w[o*18 + c];          // s = 0 (A_0 = I)
          #pragma unroll
          for (int s = 2; s <= 5; ++s) {
            float t = dv[s][v];
            acc += mlp_w[o*18 + s*3 + c] * t * t;
          }
          w4[c] = acc * inv;
        }
      }
      *(f32x4*)(W2 + i*4) = w4;
    }
  }

  int gidx = blockIdx.x*256 + tid;
  int total = gridDim.x*256;
  // Wh rows k = (s-1)*3+c for s=1..5 (15 used); k=15 holds the folded bias (paired
  // with a constant-1.0 row in y2) so P2's MFMA produces h_y + bias directly.
  for (int i = gidx; i < 96*32; i += total) {
    int o = i>>5, k = i&31;
    float inv = g1[o] / sqrtf(va1[o] + 1e-5f);
    float val = 0.f;
    if (k < 15)      val = mlp_w[o*18 + 3 + k]*inv;
    else if (k == 15) val = mlp_b[o]*inv + be1[o] - mu1[o]*inv;
    Wh[i] = (_Float16)val;
  }
  for (int i = gidx; i < 6*12*96*8; i += total) {
    int ch = i / 9216;
    int r  = i % 9216;
    int kc = r / 768;
    int r2 = r % 768;
    int m16 = r2 >> 3, j = r2 & 7;
    int k2 = kc*8 + j;            // k2 = wq*16 + cl
    float val = 0.f;
    if (k2 < 80) {
      int wq = k2 >> 4, cl = k2 & 15;
      int c = ch*16 + cl;
      float inv2 = g2[m16] / sqrtf(va2[m16] + 1e-5f);
      val = out_w[(m16*96 + c)*5 + wq] * inv2;
    }
    OWc[i] = (_Float16)val;
  }
  for (int i = gidx; i < 96; i += total) {
    float inv = g1[i] / sqrtf(va1[i] + 1e-5f);
    bp[i] = mlp_b[i]*inv + be1[i] - mu1[i]*inv;
    float inv2 = g2[i] / sqrtf(va2[i] + 1e-5f);
    ob[i] = out_b[i]*inv2 + be2[i] - mu2[i]*inv2;
  }
}

// LDS layout (bytes)
#define Y2_OFF 0        // f16 [2][128][8]   y2[kc][col3=tl*32+v][j], kz'=(s-1)*3+c (15 used; row 15 = 1.0)
#define HB_OFF 4096     // f16 [10][128][8]  h chunks, col2 = tl*32+v  (per-wave 32-col slices)
#define XW_OFF 24576    // f16 [16][136]     xw[col=(c*4+tl)][u=w*25+v]  (tail 128..135 zeroed)
#define XS_OFF 28928    // f16 [16][40]      xs[col][i] window sums
#define SM_BYTES 30208

// bounds (256,3): (256,4) forced vgpr+agpr <= 128 -> scratch spills (round-1 lesson).
__global__ __launch_bounds__(256, 3) void msg3d_main(const float* __restrict__ x,
    const char* __restrict__ ws, float* __restrict__ out) {
  __shared__ __align__(16) char smem[SM_BYTES];
  _Float16* y2 = (_Float16*)(smem + Y2_OFF);
  _Float16* hB = (_Float16*)(smem + HB_OFF);
  _Float16* xw = (_Float16*)(smem + XW_OFF);
  _Float16* xs = (_Float16*)(smem + XS_OFF);

  const int tid = threadIdx.x;
  const int wid = tid>>6, lane = tid&63, quad = lane>>4, l16 = lane&15;
  const int n = blockIdx.x / NT, t0 = (blockIdx.x % NT)*TB;
  const _Float16* AyG = (const _Float16*)(ws + AY_OFF);
  const _Float16* WhG = (const _Float16*)(ws + WH_OFF);
  const _Float16* OWG = (const _Float16*)(ws + OWC_OFF);
  const float* obG  = (const float*)(ws + OB_OFF);
  const float* W2G  = (const float*)(ws + W2_OFF);
  const f32x4 fzero = {0.f,0.f,0.f,0.f};
  const f16x8 hzero = {(_Float16)0,(_Float16)0,(_Float16)0,(_Float16)0,
                       (_Float16)0,(_Float16)0,(_Float16)0,(_Float16)0};

  // P0: stage xw (+ zero tail cols 128..135 so unguarded xb hoist reads 0);
  //     zero y2; plant the constant-1.0 bias row (kz'=15 -> kc=1, j=7)
  for (int i = tid; i < 2048; i += 256) {
    int col = i>>7, u = i&127;
    float val = 0.f;
    if (col < 12 && u < 125) {
      int c = col>>2, tt = col&3;
      int w = u/25, v = u - w*25;
      int fr = t0 + tt + w - 2;
      if (fr >= 0 && fr < T_F) val = x[((n*3+c)*T_F + fr)*25 + v];
    }
    xw[col*136 + u] = (_Float16)val;
  }
  if (tid < 128) xw[(tid>>3)*136 + 128 + (tid&7)] = (_Float16)0.f;
  *(f32x4*)(y2 + tid*8) = fzero;
  if (tid >= 128) y2[tid*8 + 7] = (_Float16)1.0f;   // row kz'=15 == 1.0 for every col
  __syncthreads();

  // P1: xs[col][i] = sum_w xw[col][w*25+i]  (f32 accumulate, f16 store; pad i 25..31 = 0)
  for (int i = tid; i < 512; i += 256) {
    int col = i>>5, k = i&31;
    float val = 0.f;
    if (k < 25) {
      float a = 0.f;
      #pragma unroll
      for (int w = 0; w < 5; ++w) a += (float)xw[col*136 + w*25 + k];
      val = a;
    }
    xs[col*40 + k] = (_Float16)val;
  }
  __syncthreads();

  // y-GEMM: y[(s,v)][(c,tl)] = sum_i Ay[(s,v)][i] * xs[(c,tl)][i]  (M=128, N=16, K=32)
  {
    const int m0 = wid*2;
    f16x8 bx = *(f16x8*)(xs + l16*40 + quad*8);
    f16x8 a0 = *(const f16x8*)(AyG + (quad*128 + m0*16 + l16)*8);
    f16x8 a1 = *(const f16x8*)(AyG + (quad*128 + m0*16 + 16 + l16)*8);
    f32x4 y0 = __builtin_amdgcn_mfma_f32_16x16x32_f16(a0, bx, fzero, 0, 0, 0);
    f32x4 y1 = __builtin_amdgcn_mfma_f32_16x16x32_f16(a1, bx, fzero, 0, 0, 0);
    if (l16 < 12) {
      int c = l16>>2, tt = l16&3;
      #pragma unroll
      for (int half = 0; half < 2; ++half) {
        f32x4 zz = half ? y1 : y0;
        int mt = m0 + half;
        #pragma unroll
        for (int r = 0; r < 4; ++r) {
          int m = mt*16 + quad*4 + r;
          if (m < 125) {
            int s1 = m/25;                 // 0..4  <->  s = 1..5
            int v  = m - s1*25;
            int kzp = s1*3 + c;            // 0..14
            y2[((kzp>>3)*128 + tt*32 + v)*8 + (kzp&7)] = (_Float16)zz[r];
          }
        }
      }
    }
  }

  // Hoist BOTH per-lane xw slices (v=l16 and v=16+l16): 30 regs, reused 6x.
  // Safe unguarded: max u = 100+31 = 131 <= 135, tail zeroed in P0.
  const int tl = wid;
  float xa[5][3], xb[5][3];
  #pragma unroll
  for (int w = 0; w < 5; ++w)
    #pragma unroll
    for (int c = 0; c < 3; ++c) {
      xa[w][c] = (float)xw[(c*4+tl)*136 + w*25 + l16];
      xb[w][c] = (float)xw[(c*4+tl)*136 + w*25 + 16 + l16];
    }
  __syncthreads();
  // ===== Last barrier. Waves fully independent from here (round-3 invariant). =====

  // cacc initialized with the folded output bias
  f32x4 cacc[6][2];
  #pragma unroll
  for (int m = 0; m < 6; ++m) {
    f32x4 ob4 = *(const f32x4*)(obG + m*16 + quad*4);
    cacc[m][0] = ob4; cacc[m][1] = ob4;
  }

  // OW software pipeline: two 3-wide register buffers, each half-step's loads
  // issued one full step (12 MFMAs + P2) ahead of use. ch loop FULLY unrolled
  // so all OW/Wh/W2 addresses are compile-time and prefetch crosses chunk bounds.
  f16x8 owA[3], owB[3];
  #pragma unroll
  for (int m = 0; m < 3; ++m)
    owA[m] = *(const f16x8*)(OWG + (quad*96 + m*16 + l16)*8);
  #pragma unroll
  for (int m = 0; m < 3; ++m)
    owB[m] = *(const f16x8*)(OWG + (quad*96 + (m+3)*16 + l16)*8);

  #pragma unroll
  for (int ch = 0; ch < 6; ++ch) {
    // ---- P2(ch): h = Wh@y2 (bias via K-row 15) + diag(W2,x); ReLU -> hB ----
    // (ch,kt=0)'s OW loads are in flight during this whole phase.
    f16x8 wa = *(const f16x8*)(WhG + (ch*16 + l16)*32 + quad*8);
    const int col3 = wid*32 + l16;
    f16x8 zb0 = hzero, zb1 = hzero;
    if (quad < 2) {
      zb0 = *(f16x8*)(y2 + (quad*128 + col3)*8);
      zb1 = *(f16x8*)(y2 + (quad*128 + col3 + 16)*8);
    }
    f32x4 hc0 = __builtin_amdgcn_mfma_f32_16x16x32_f16(wa, zb0, fzero, 0, 0, 0);
    f32x4 hc1 = __builtin_amdgcn_mfma_f32_16x16x32_f16(wa, zb1, fzero, 0, 0, 0);
    // W2 loads: unconditional, grouped, issued before the epilogues consume hc.
    const float* w2b = W2G + (ch*16 + quad*4)*128;
    f32x4 w20[4], w21[4];
    #pragma unroll
    for (int r = 0; r < 4; ++r) w20[r] = *(const f32x4*)(w2b + r*128 + l16*4);
    #pragma unroll
    for (int r = 0; r < 4; ++r) w21[r] = *(const f32x4*)(w2b + r*128 + (16+l16)*4);
    // epilogue nn=0: v = l16 (< 25 always, no guard)
    {
      const int col2 = wid*32 + l16;
      #pragma unroll
      for (int wq = 0; wq < 5; ++wq) {
        f16x4 hv;
        #pragma unroll
        for (int r = 0; r < 4; ++r) {
          float h = hc0[r] + w20[r][0]*xa[wq][0] + w20[r][1]*xa[wq][1] + w20[r][2]*xa[wq][2];
          hv[r] = (_Float16)(h > 0.0f ? h : 0.0f);
        }
        const int k2b = wq*16 + quad*4;
        *(f16x4*)(hB + ((k2b>>3)*128 + col2)*8 + (k2b&7)) = hv;
      }
    }
    // epilogue nn=1: v = 16+l16, active l16 < 9
    if (l16 < 9) {
      const int col2 = wid*32 + 16 + l16;
      #pragma unroll
      for (int wq = 0; wq < 5; ++wq) {
        f16x4 hv;
        #pragma unroll
        for (int r = 0; r < 4; ++r) {
          float h = hc1[r] + w21[r][0]*xb[wq][0] + w21[r][1]*xb[wq][1] + w21[r][2]*xb[wq][2];
          hv[r] = (_Float16)(h > 0.0f ? h : 0.0f);
        }
        const int k2b = wq*16 + quad*4;
        *(f16x4*)(hB + ((k2b>>3)*128 + col2)*8 + (k2b&7)) = hv;
      }
    }

    // ---- P3(ch): C += OW @ hB, OW double-buffered at half-step granularity ----
    #pragma unroll
    for (int kt = 0; kt < 3; ++kt) {
      const int col0 = wid*32 + l16;
      f16x8 b0 = hzero, b1 = hzero;
      if (kt < 2 || quad < 2) {              // kc = kt*4+quad < 10
        const int kc = kt*4 + quad;
        b0 = *(f16x8*)(hB + (kc*128 + col0)*8);
        b1 = *(f16x8*)(hB + (kc*128 + col0 + 16)*8);
      }
      const bool last = (ch == 5 && kt == 2);
      const int nch = (kt == 2) ? ch + 1 : ch;
      const int nkt = (kt == 2) ? 0 : kt + 1;

      __builtin_amdgcn_s_setprio(1);
      #pragma unroll
      for (int m = 0; m < 3; ++m) {
        cacc[m][0] = __builtin_amdgcn_mfma_f32_16x16x32_f16(owA[m], b0, cacc[m][0], 0, 0, 0);
        cacc[m][1] = __builtin_amdgcn_mfma_f32_16x16x32_f16(owA[m], b1, cacc[m][1], 0, 0, 0);
      }
      __builtin_amdgcn_s_setprio(0);
      if (!last) {
        #pragma unroll
        for (int m = 0; m < 3; ++m)
          owA[m] = *(const f16x8*)(OWG + ((nch*12 + nkt*4 + quad)*96 + m*16 + l16)*8);
      }
      __builtin_amdgcn_s_setprio(1);
      #pragma unroll
      for (int m = 0; m < 3; ++m) {
        cacc[m+3][0] = __builtin_amdgcn_mfma_f32_16x16x32_f16(owB[m], b0, cacc[m+3][0], 0, 0, 0);
        cacc[m+3][1] = __builtin_amdgcn_mfma_f32_16x16x32_f16(owB[m], b1, cacc[m+3][1], 0, 0, 0);
      }
      __builtin_amdgcn_s_setprio(0);
      if (!last) {
        #pragma unroll
        for (int m = 0; m < 3; ++m)
          owB[m] = *(const f16x8*)(OWG + ((nch*12 + nkt*4 + quad)*96 + (m+3)*16 + l16)*8);
      }
    }
  }

  // Epilogue (bias already in cacc). cacc col = wid*32 + nn*16 + l16 -> tte = wid, v = nn*16+l16.
  #pragma unroll
  for (int nn = 0; nn < 2; ++nn) {
    int v = nn*16 + l16;
    if (v < 25) {
      #pragma unroll
      for (int m = 0; m < 6; ++m) {
        #pragma unroll
        for (int r = 0; r < 4; ++r) {
          int o2 = m*16 + quad*4 + r;
          out[((n*96 + o2)*T_F + t0 + wid)*25 + v] = cacc[m][nn][r];
        }
      }
    }
  }
}

extern "C" void kernel_launch(void* const* d_in, const int* in_sizes, int n_in,
                              void* d_out, int out_size, void* d_ws, size_t ws_size,
                              hipStream_t stream) {
  const float* x     = (const float*)d_in[0];
  const float* mlp_w = (const float*)d_in[1];
  const float* mlp_b = (const float*)d_in[2];
  const float* g1    = (const float*)d_in[3];
  const float* be1   = (const float*)d_in[4];
  const float* mu1   = (const float*)d_in[5];
  const float* va1   = (const float*)d_in[6];
  const float* out_w = (const float*)d_in[7];
  const float* out_b = (const float*)d_in[8];
  const float* g2    = (const float*)d_in[9];
  const float* be2   = (const float*)d_in[10];
  const float* mu2   = (const float*)d_in[11];
  const float* va2   = (const float*)d_in[12];
  float* out = (float*)d_out;
  char*  ws  = (char*)d_ws;

  setup_kernel<<<64, 256, 0, stream>>>(mlp_w, mlp_b, g1, be1, mu1, va1,
                                       out_w, out_b, g2, be2, mu2, va2, ws);
  msg3d_main<<<N_B * NT, 256, 0, stream>>>(x, ws, out);
}

// Round 5
// 326.426 us; speedup vs baseline: 1.2942x; 1.2942x over previous
//
#include <hip/hip_runtime.h>

typedef __attribute__((ext_vector_type(8))) _Float16 f16x8;
typedef __attribute__((ext_vector_type(4))) _Float16 f16x4;
typedef __attribute__((ext_vector_type(4))) float f32x4;

#define N_B 64
#define T_F 300
#define TB 4
#define NT (T_F/TB)

// ws byte offsets
#define AY_OFF  0        // f16 [4][128][8]    y-GEMM A operand, K-chunked
#define WH_OFF  8192     // f16 [96][32]       folded mlp weight; k=0..14: Wh[(s-1)*3+c], k=15: folded bias
#define OWC_OFF 14336    // f16 [6][12][96][8] folded out weight, chunked (18432 B per ch)
#define BP_OFF  124928   // float[96]          (unused by main now; kept for layout stability)
#define OB_OFF  125312   // float[96]
#define W2_OFF  125696   // float[96][32][4]   diag weights W2[o][v][c] (c<3 used)

__device__ __constant__ int EDGES[24][2] = {
  {1,2},{2,21},{3,21},{4,3},{5,21},{6,5},{7,6},{8,7},{9,21},{10,9},{11,10},{12,11},
  {13,1},{14,13},{15,14},{16,15},{17,1},{18,17},{19,18},{20,19},{22,23},{23,8},{24,25},{25,12}
};

__global__ void setup_kernel(const float* __restrict__ mlp_w, const float* __restrict__ mlp_b,
    const float* __restrict__ g1, const float* __restrict__ be1,
    const float* __restrict__ mu1, const float* __restrict__ va1,
    const float* __restrict__ out_w, const float* __restrict__ out_b,
    const float* __restrict__ g2, const float* __restrict__ be2,
    const float* __restrict__ mu2, const float* __restrict__ va2,
    char* __restrict__ wsb) {
  _Float16* Ay  = (_Float16*)(wsb + AY_OFF);
  _Float16* Wh  = (_Float16*)(wsb + WH_OFF);
  _Float16* OWc = (_Float16*)(wsb + OWC_OFF);
  float* bp  = (float*)(wsb + BP_OFF);
  float* ob  = (float*)(wsb + OB_OFF);
  float* W2  = (float*)(wsb + W2_OFF);
  int tid = threadIdx.x;

  if (blockIdx.x == 0) {
    // A_large = J5 (x) B with B = A+I  =>  scale s reduces to 25-node graph:
    //   s=0: A_s = I;  s=1: M = J(x)B;  s>=2: M = J(x)(R_s\R_{s-1}) + I.
    __shared__ unsigned int Rk[6][25];
    __shared__ unsigned int Gs[6][25];
    __shared__ float dv[6][25];
    if (tid < 25) {
      unsigned int m = 1u << tid;
      for (int e = 0; e < 24; ++e) {
        int a = EDGES[e][0]-1, b = EDGES[e][1]-1;
        if (a == tid) m |= 1u<<b;
        if (b == tid) m |= 1u<<a;
      }
      Gs[1][tid] = m;   // B masks (incl. self)
      Rk[1][tid] = m;
    }
    __syncthreads();
    for (int k = 2; k <= 5; ++k) {
      if (tid < 25) {
        unsigned int p = Rk[k-1][tid], nm = p;
        for (int j = 0; j < 25; ++j) if ((p>>j)&1u) nm |= Gs[1][j];
        Rk[k][tid] = nm;
      }
      __syncthreads();
    }
    if (tid < 25) {
      for (int s = 1; s <= 5; ++s) {
        unsigned int g = (s==1) ? Gs[1][tid] : (Rk[s][tid] & ~Rk[s-1][tid]);
        if (s >= 2) Gs[s][tid] = g;
        int d = 5*__popc(g) + ((s>=2)?1:0);
        dv[s][tid] = (d>0) ? (float)(1.0/sqrt((double)d)) : 0.0f;
      }
    }
    __syncthreads();
    // Ay: [kc=0..3][row=0..127][j=0..7], row=(s-1)*25+v for s=1..5, i = kc*8+j
    for (int idx = tid; idx < 4096; idx += 256) {
      int kc = idx >> 10, row = (idx>>3)&127, j = idx&7;
      int i = kc*8 + j;
      float val = 0.f;
      if (row < 125 && i < 25) {
        int s = 1 + row/25, v = row - (s-1)*25;
        if ((Gs[s][v] >> i) & 1u) val = dv[s][v]*dv[s][i];
      }
      Ay[idx] = (_Float16)val;
    }
    // W2[o][v][c]: s=0 identity + s>=2 diagonal corrections, BN-folded
    for (int i = tid; i < 96*32; i += 256) {
      int o = i>>5, v = i&31;
      f32x4 w4 = {0.f,0.f,0.f,0.f};
      if (v < 25) {
        float inv = g1[o] / sqrtf(va1[o] + 1e-5f);
        #pragma unroll
        for (int c = 0; c < 3; ++c) {
          float acc = mlp_w[o*18 + c];          // s = 0 (A_0 = I)
          #pragma unroll
          for (int s = 2; s <= 5; ++s) {
            float t = dv[s][v];
            acc += mlp_w[o*18 + s*3 + c] * t * t;
          }
          w4[c] = acc * inv;
        }
      }
      *(f32x4*)(W2 + i*4) = w4;
    }
  }

  int gidx = blockIdx.x*256 + tid;
  int total = gridDim.x*256;
  // Wh rows k = (s-1)*3+c for s=1..5 (15 used); k=15 holds the folded bias (paired
  // with a constant-1.0 row in y2) so P2's MFMA produces h_y + bias directly.
  for (int i = gidx; i < 96*32; i += total) {
    int o = i>>5, k = i&31;
    float inv = g1[o] / sqrtf(va1[o] + 1e-5f);
    float val = 0.f;
    if (k < 15)      val = mlp_w[o*18 + 3 + k]*inv;
    else if (k == 15) val = mlp_b[o]*inv + be1[o] - mu1[o]*inv;
    Wh[i] = (_Float16)val;
  }
  for (int i = gidx; i < 6*12*96*8; i += total) {
    int ch = i / 9216;
    int r  = i % 9216;
    int kc = r / 768;
    int r2 = r % 768;
    int m16 = r2 >> 3, j = r2 & 7;
    int k2 = kc*8 + j;            // k2 = wq*16 + cl
    float val = 0.f;
    if (k2 < 80) {
      int wq = k2 >> 4, cl = k2 & 15;
      int c = ch*16 + cl;
      float inv2 = g2[m16] / sqrtf(va2[m16] + 1e-5f);
      val = out_w[(m16*96 + c)*5 + wq] * inv2;
    }
    OWc[i] = (_Float16)val;
  }
  for (int i = gidx; i < 96; i += total) {
    float inv = g1[i] / sqrtf(va1[i] + 1e-5f);
    bp[i] = mlp_b[i]*inv + be1[i] - mu1[i]*inv;
    float inv2 = g2[i] / sqrtf(va2[i] + 1e-5f);
    ob[i] = out_b[i]*inv2 + be2[i] - mu2[i]*inv2;
  }
}

// LDS layout (bytes)
#define Y2_OFF 0        // f16 [2][128][8]   y2[kc][col3=tl*32+v][j], kz'=(s-1)*3+c (15 used; row 15 = 1.0)
#define HB_OFF 4096     // f16 [10][128][8]  h chunks, col2 = tl*32+v  (per-wave 32-col slices)
#define XW_OFF 24576    // f16 [16][136]     xw[col=(c*4+tl)][u=w*25+v]
#define XS_OFF 28928    // f16 [16][40]      xs[col][i] window sums
#define ZP_OFF 30208    // f16 zero strip (16 B)
#define OWS_OFF 30224   // f16 [12][96][8]   current chunk's folded out weight (18432 B)
#define SM_BYTES 48656

// Stage OW chunk ch_ into LDS: 18 segments of 1 KB, each one global_load_lds
// (linear dest = wave-uniform base + lane*16; per-lane global src). Zero VGPR cost.
#define OW_STAGE(ch_) do {                                                        \
    const char* gseg_ = ws + OWC_OFF + (ch_)*18432 + lane*16;                     \
    char* lseg_ = smem + OWS_OFF;                                                 \
    for (int seg_ = wid; seg_ < 18; seg_ += 4)                                    \
      __builtin_amdgcn_global_load_lds(                                           \
        (const __attribute__((address_space(1))) unsigned int*)(gseg_ + seg_*1024),\
        (__attribute__((address_space(3))) unsigned int*)(lseg_ + seg_*1024),     \
        16, 0, 0);                                                                \
  } while (0)

// bounds (256,3): (256,4) forced vgpr+agpr <= 128 -> scratch spills (round-1 lesson).
__global__ __launch_bounds__(256, 3) void msg3d_main(const float* __restrict__ x,
    const char* __restrict__ ws, float* __restrict__ out) {
  __shared__ __align__(16) char smem[SM_BYTES];
  _Float16* y2 = (_Float16*)(smem + Y2_OFF);
  _Float16* hB = (_Float16*)(smem + HB_OFF);
  _Float16* xw = (_Float16*)(smem + XW_OFF);
  _Float16* xs = (_Float16*)(smem + XS_OFF);
  _Float16* zp = (_Float16*)(smem + ZP_OFF);
  _Float16* owS = (_Float16*)(smem + OWS_OFF);

  const int tid = threadIdx.x;
  const int wid = tid>>6, lane = tid&63, quad = lane>>4, l16 = lane&15;
  const int n = blockIdx.x / NT, t0 = (blockIdx.x % NT)*TB;
  const _Float16* AyG = (const _Float16*)(ws + AY_OFF);
  const _Float16* WhG = (const _Float16*)(ws + WH_OFF);
  const float* obG  = (const float*)(ws + OB_OFF);
  const float* W2G  = (const float*)(ws + W2_OFF);
  const f32x4 fzero = {0.f,0.f,0.f,0.f};

  // Stage OW chunk 0 immediately: latency fully hidden under P0/P1/y-GEMM.
  OW_STAGE(0);

  // P0: stage xw; zero y2; plant the constant-1.0 bias row (kz'=15 -> kc=1, j=7)
  for (int i = tid; i < 2048; i += 256) {
    int col = i>>7, u = i&127;
    float val = 0.f;
    if (col < 12 && u < 125) {
      int c = col>>2, tt = col&3;
      int w = u/25, v = u - w*25;
      int fr = t0 + tt + w - 2;
      if (fr >= 0 && fr < T_F) val = x[((n*3+c)*T_F + fr)*25 + v];
    }
    xw[col*136 + u] = (_Float16)val;
  }
  *(f32x4*)(y2 + tid*8) = fzero;
  if (tid >= 128) y2[tid*8 + 7] = (_Float16)1.0f;   // row kz'=15 == 1.0 for every col
  if (tid == 0) *(f32x4*)zp = fzero;
  __syncthreads();

  // P1: xs[col][i] = sum_w xw[col][w*25+i]  (f32 accumulate, f16 store; pad i 25..31 = 0)
  for (int i = tid; i < 512; i += 256) {
    int col = i>>5, k = i&31;
    float val = 0.f;
    if (k < 25) {
      float a = 0.f;
      #pragma unroll
      for (int w = 0; w < 5; ++w) a += (float)xw[col*136 + w*25 + k];
      val = a;
    }
    xs[col*40 + k] = (_Float16)val;
  }
  __syncthreads();

  // y-GEMM: y[(s,v)][(c,tl)] = sum_i Ay[(s,v)][i] * xs[(c,tl)][i]  (M=128, N=16, K=32)
  {
    const int m0 = wid*2;
    f16x8 bx = *(f16x8*)(xs + l16*40 + quad*8);
    f16x8 a0 = *(const f16x8*)(AyG + (quad*128 + m0*16 + l16)*8);
    f16x8 a1 = *(const f16x8*)(AyG + (quad*128 + m0*16 + 16 + l16)*8);
    f32x4 y0 = __builtin_amdgcn_mfma_f32_16x16x32_f16(a0, bx, fzero, 0, 0, 0);
    f32x4 y1 = __builtin_amdgcn_mfma_f32_16x16x32_f16(a1, bx, fzero, 0, 0, 0);
    if (l16 < 12) {
      int c = l16>>2, tt = l16&3;
      #pragma unroll
      for (int half = 0; half < 2; ++half) {
        f32x4 zz = half ? y1 : y0;
        int mt = m0 + half;
        #pragma unroll
        for (int r = 0; r < 4; ++r) {
          int m = mt*16 + quad*4 + r;
          if (m < 125) {
            int s1 = m/25;                 // 0..4  <->  s = 1..5
            int v  = m - s1*25;
            int kzp = s1*3 + c;            // 0..14
            y2[((kzp>>3)*128 + tt*32 + v)*8 + (kzp&7)] = (_Float16)zz[r];
          }
        }
      }
    }
  }

  // Hoist ONLY the nn=0 per-lane xw values (v=l16<16): 15 regs. The nn=1 half
  // reads xw from LDS at use.
  const int tl = wid;
  float xa[5][3];
  #pragma unroll
  for (int w = 0; w < 5; ++w)
    #pragma unroll
    for (int c = 0; c < 3; ++c)
      xa[w][c] = (float)xw[(c*4+tl)*136 + w*25 + l16];
  __syncthreads();
  // y2 ready; owS[0] landed (every __syncthreads drains vmcnt).

  // cacc initialized with the folded output bias
  f32x4 cacc[6][2];
  #pragma unroll
  for (int m = 0; m < 6; ++m) {
    f32x4 ob4 = *(const f32x4*)(obG + m*16 + quad*4);
    cacc[m][0] = ob4; cacc[m][1] = ob4;
  }

  // Per c-chunk: [stage OW(ch) for ch>0 — latency hides under P2]
  //              P2 h = Wh@y2 (bias via K-row 15; + per-v diag via W2; ReLU) -> hB
  //              barrier (owS ready) ; P3 C += owS @ hB ; barrier (owS free)
  for (int ch = 0; ch < 6; ++ch) {
    if (ch > 0) OW_STAGE(ch);

    f16x8 wa = *(const f16x8*)(WhG + (ch*16 + l16)*32 + quad*8);
    const float* w2base = W2G + (ch*16 + quad*4)*128;   // o-stride = 32*4 floats

    #pragma unroll
    for (int nn = 0; nn < 2; ++nn) {
      int col3 = wid*32 + nn*16 + l16;
      const _Float16* zsrc = (quad < 2) ? (y2 + (quad*128 + col3)*8) : zp;
      f16x8 zb = *(f16x8*)zsrc;
      f32x4 hc = __builtin_amdgcn_mfma_f32_16x16x32_f16(wa, zb, fzero, 0, 0, 0);
      int v = nn*16 + l16;
      if (v < 25) {
        int col2 = tl*32 + v;           // per-wave 32-col slice
        f32x4 w2[4];
        #pragma unroll
        for (int r = 0; r < 4; ++r) w2[r] = *(const f32x4*)(w2base + r*128 + v*4);
        #pragma unroll
        for (int wq = 0; wq < 5; ++wq) {
          float x0, x1, x2;
          if (nn == 0) { x0 = xa[wq][0]; x1 = xa[wq][1]; x2 = xa[wq][2]; }
          else {
            x0 = (float)xw[(0*4+tl)*136 + wq*25 + v];
            x1 = (float)xw[(1*4+tl)*136 + wq*25 + v];
            x2 = (float)xw[(2*4+tl)*136 + wq*25 + v];
          }
          f16x4 hv;
          #pragma unroll
          for (int r = 0; r < 4; ++r) {
            float h = hc[r] + w2[r][0]*x0 + w2[r][1]*x1 + w2[r][2]*x2;
            hv[r] = (_Float16)(h > 0.0f ? h : 0.0f);
          }
          int k2b = wq*16 + quad*4;
          *(f16x4*)(hB + ((k2b>>3)*128 + col2)*8 + (k2b&7)) = hv;
        }
      }
    }
    __syncthreads();   // drains OW staging (vmcnt); owS[ch] ready

    #pragma unroll
    for (int kt = 0; kt < 3; ++kt) {
      int kc = kt*4 + quad;
      int col0 = wid*32 + l16;
      const _Float16* h0 = (kc < 10) ? (hB + (kc*128 + col0)*8)      : zp;
      const _Float16* h1 = (kc < 10) ? (hB + (kc*128 + col0 + 16)*8) : zp;
      f16x8 b0 = *(f16x8*)h0;
      f16x8 b1 = *(f16x8*)h1;
      #pragma unroll
      for (int m = 0; m < 6; ++m) {
        f16x8 a = *(const f16x8*)(owS + (kc*96 + m*16 + l16)*8);
        cacc[m][0] = __builtin_amdgcn_mfma_f32_16x16x32_f16(a, b0, cacc[m][0], 0, 0, 0);
        cacc[m][1] = __builtin_amdgcn_mfma_f32_16x16x32_f16(a, b1, cacc[m][1], 0, 0, 0);
      }
    }
    if (ch < 5) __syncthreads();   // all waves done reading owS before restage
  }

  // Epilogue (bias already in cacc). cacc col = wid*32 + nn*16 + l16 -> tte = wid, v = nn*16+l16.
  #pragma unroll
  for (int nn = 0; nn < 2; ++nn) {
    int v = nn*16 + l16;
    if (v < 25) {
      #pragma unroll
      for (int m = 0; m < 6; ++m) {
        #pragma unroll
        for (int r = 0; r < 4; ++r) {
          int o2 = m*16 + quad*4 + r;
          out[((n*96 + o2)*T_F + t0 + wid)*25 + v] = cacc[m][nn][r];
        }
      }
    }
  }
}

extern "C" void kernel_launch(void* const* d_in, const int* in_sizes, int n_in,
                              void* d_out, int out_size, void* d_ws, size_t ws_size,
                              hipStream_t stream) {
  const float* x     = (const float*)d_in[0];
  const float* mlp_w = (const float*)d_in[1];
  const float* mlp_b = (const float*)d_in[2];
  const float* g1    = (const float*)d_in[3];
  const float* be1   = (const float*)d_in[4];
  const float* mu1   = (const float*)d_in[5];
  const float* va1   = (const float*)d_in[6];
  const float* out_w = (const float*)d_in[7];
  const float* out_b = (const float*)d_in[8];
  const float* g2    = (const float*)d_in[9];
  const float* be2   = (const float*)d_in[10];
  const float* mu2   = (const float*)d_in[11];
  const float* va2   = (const float*)d_in[12];
  float* out = (float*)d_out;
  char*  ws  = (char*)d_ws;

  setup_kernel<<<64, 256, 0, stream>>>(mlp_w, mlp_b, g1, be1, mu1, va1,
                                       out_w, out_b, g2, be2, mu2, va2, ws);
  msg3d_main<<<N_B * NT, 256, 0, stream>>>(x, ws, out);
}

// Round 6
// 325.994 us; speedup vs baseline: 1.2959x; 1.0013x over previous
//
#include <hip/hip_runtime.h>

typedef __attribute__((ext_vector_type(8))) _Float16 f16x8;
typedef __attribute__((ext_vector_type(4))) _Float16 f16x4;
typedef __attribute__((ext_vector_type(4))) float f32x4;

#define N_B 64
#define T_F 300
#define TB 4
#define NT (T_F/TB)

// ws byte offsets
#define AY_OFF  0        // f16 [4][128][8]    y-GEMM A operand, K-chunked
#define WH_OFF  8192     // f16 [96][32]       folded mlp weight; k=0..14: Wh[(s-1)*3+c], k=15: folded bias
#define OWC_OFF 14336    // f16 [6][12][96][8] folded out weight, chunked (18432 B per ch; kc>=10 zero)
#define BP_OFF  124928   // float[96]          (unused by main now; kept for layout stability)
#define OB_OFF  125312   // float[96]
#define W2_OFF  125696   // float[96][32][4]   diag weights W2[o][v][c] (c<3 used)

__device__ __constant__ int EDGES[24][2] = {
  {1,2},{2,21},{3,21},{4,3},{5,21},{6,5},{7,6},{8,7},{9,21},{10,9},{11,10},{12,11},
  {13,1},{14,13},{15,14},{16,15},{17,1},{18,17},{19,18},{20,19},{22,23},{23,8},{24,25},{25,12}
};

__global__ void setup_kernel(const float* __restrict__ mlp_w, const float* __restrict__ mlp_b,
    const float* __restrict__ g1, const float* __restrict__ be1,
    const float* __restrict__ mu1, const float* __restrict__ va1,
    const float* __restrict__ out_w, const float* __restrict__ out_b,
    const float* __restrict__ g2, const float* __restrict__ be2,
    const float* __restrict__ mu2, const float* __restrict__ va2,
    char* __restrict__ wsb) {
  _Float16* Ay  = (_Float16*)(wsb + AY_OFF);
  _Float16* Wh  = (_Float16*)(wsb + WH_OFF);
  _Float16* OWc = (_Float16*)(wsb + OWC_OFF);
  float* bp  = (float*)(wsb + BP_OFF);
  float* ob  = (float*)(wsb + OB_OFF);
  float* W2  = (float*)(wsb + W2_OFF);
  int tid = threadIdx.x;

  if (blockIdx.x == 0) {
    // A_large = J5 (x) B with B = A+I  =>  scale s reduces to 25-node graph:
    //   s=0: A_s = I;  s=1: M = J(x)B;  s>=2: M = J(x)(R_s\R_{s-1}) + I.
    __shared__ unsigned int Rk[6][25];
    __shared__ unsigned int Gs[6][25];
    __shared__ float dv[6][25];
    if (tid < 25) {
      unsigned int m = 1u << tid;
      for (int e = 0; e < 24; ++e) {
        int a = EDGES[e][0]-1, b = EDGES[e][1]-1;
        if (a == tid) m |= 1u<<b;
        if (b == tid) m |= 1u<<a;
      }
      Gs[1][tid] = m;   // B masks (incl. self)
      Rk[1][tid] = m;
    }
    __syncthreads();
    for (int k = 2; k <= 5; ++k) {
      if (tid < 25) {
        unsigned int p = Rk[k-1][tid], nm = p;
        for (int j = 0; j < 25; ++j) if ((p>>j)&1u) nm |= Gs[1][j];
        Rk[k][tid] = nm;
      }
      __syncthreads();
    }
    if (tid < 25) {
      for (int s = 1; s <= 5; ++s) {
        unsigned int g = (s==1) ? Gs[1][tid] : (Rk[s][tid] & ~Rk[s-1][tid]);
        if (s >= 2) Gs[s][tid] = g;
        int d = 5*__popc(g) + ((s>=2)?1:0);
        dv[s][tid] = (d>0) ? (float)(1.0/sqrt((double)d)) : 0.0f;
      }
    }
    __syncthreads();
    // Ay: [kc=0..3][row=0..127][j=0..7], row=(s-1)*25+v for s=1..5, i = kc*8+j
    for (int idx = tid; idx < 4096; idx += 256) {
      int kc = idx >> 10, row = (idx>>3)&127, j = idx&7;
      int i = kc*8 + j;
      float val = 0.f;
      if (row < 125 && i < 25) {
        int s = 1 + row/25, v = row - (s-1)*25;
        if ((Gs[s][v] >> i) & 1u) val = dv[s][v]*dv[s][i];
      }
      Ay[idx] = (_Float16)val;
    }
    // W2[o][v][c]: s=0 identity + s>=2 diagonal corrections, BN-folded
    for (int i = tid; i < 96*32; i += 256) {
      int o = i>>5, v = i&31;
      f32x4 w4 = {0.f,0.f,0.f,0.f};
      if (v < 25) {
        float inv = g1[o] / sqrtf(va1[o] + 1e-5f);
        #pragma unroll
        for (int c = 0; c < 3; ++c) {
          float acc = mlp_w[o*18 + c];          // s = 0 (A_0 = I)
          #pragma unroll
          for (int s = 2; s <= 5; ++s) {
            float t = dv[s][v];
            acc += mlp_w[o*18 + s*3 + c] * t * t;
          }
          w4[c] = acc * inv;
        }
      }
      *(f32x4*)(W2 + i*4) = w4;
    }
  }

  int gidx = blockIdx.x*256 + tid;
  int total = gridDim.x*256;
  // Wh rows k = (s-1)*3+c for s=1..5 (15 used); k=15 holds the folded bias (paired
  // with a constant-1.0 row in y2) so P2's MFMA produces h_y + bias directly.
  for (int i = gidx; i < 96*32; i += total) {
    int o = i>>5, k = i&31;
    float inv = g1[o] / sqrtf(va1[o] + 1e-5f);
    float val = 0.f;
    if (k < 15)      val = mlp_w[o*18 + 3 + k]*inv;
    else if (k == 15) val = mlp_b[o]*inv + be1[o] - mu1[o]*inv;
    Wh[i] = (_Float16)val;
  }
  for (int i = gidx; i < 6*12*96*8; i += total) {
    int ch = i / 9216;
    int r  = i % 9216;
    int kc = r / 768;
    int r2 = r % 768;
    int m16 = r2 >> 3, j = r2 & 7;
    int k2 = kc*8 + j;            // k2 = wq*16 + cl
    float val = 0.f;
    if (k2 < 80) {
      int wq = k2 >> 4, cl = k2 & 15;
      int c = ch*16 + cl;
      float inv2 = g2[m16] / sqrtf(va2[m16] + 1e-5f);
      val = out_w[(m16*96 + c)*5 + wq] * inv2;
    }
    OWc[i] = (_Float16)val;
  }
  for (int i = gidx; i < 96; i += total) {
    float inv = g1[i] / sqrtf(va1[i] + 1e-5f);
    bp[i] = mlp_b[i]*inv + be1[i] - mu1[i]*inv;
    float inv2 = g2[i] / sqrtf(va2[i] + 1e-5f);
    ob[i] = out_b[i]*inv2 + be2[i] - mu2[i]*inv2;
  }
}

// LDS layout (bytes) — total 40464, rounds to 40960 (512 B granule) = 4 blocks/CU.
#define Y2_OFF 0        // f16 [2][128][8]   y2[kc][col3=tl*32+v][j] (15 rows used; row 15 = 1.0)
#define HB_OFF 4096     // f16 [10][104][8]  h chunks, col2 = tl*26+v  (per-wave 26-col slices)
#define XS_OFF 4096     // f16 [16][40]      xs — ALIASES hB head (xs dead before hB first write)
#define XW_OFF 20736    // f16 [16][136]     xw[col=(c*4+tl)][u=w*25+v]
#define ZP_OFF 25088    // f16 zero strip (16 B)
#define OWS_OFF 25104   // f16 [10][96][8]   current chunk's folded out weight (15360 B; kc>=10 dropped)
#define SM_BYTES 40464

// Stage OW chunk ch_ (first 10 kc sub-chunks = 15360 B) into LDS: 15 segments of
// 1 KB via global_load_lds (linear dest = wave-uniform base + lane*16). Zero VGPR.
#define OW_STAGE(ch_) do {                                                        \
    const char* gseg_ = ws + OWC_OFF + (ch_)*18432 + lane*16;                     \
    char* lseg_ = smem + OWS_OFF;                                                 \
    for (int seg_ = wid; seg_ < 15; seg_ += 4)                                    \
      __builtin_amdgcn_global_load_lds(                                           \
        (const __attribute__((address_space(1))) unsigned int*)(gseg_ + seg_*1024),\
        (__attribute__((address_space(3))) unsigned int*)(lseg_ + seg_*1024),     \
        16, 0, 0);                                                                \
  } while (0)

// bounds (256,3): (256,4) forced vgpr+agpr <= 128 -> scratch spills (round-1 lesson).
// Actual usage ~72+48=120 <= 128, so the register file permits 4 waves/SIMD; LDS
// (40960) is now the binding constraint at exactly 4 blocks/CU.
__global__ __launch_bounds__(256, 3) void msg3d_main(const float* __restrict__ x,
    const char* __restrict__ ws, float* __restrict__ out) {
  __shared__ __align__(16) char smem[SM_BYTES];
  _Float16* y2 = (_Float16*)(smem + Y2_OFF);
  _Float16* hB = (_Float16*)(smem + HB_OFF);
  _Float16* xw = (_Float16*)(smem + XW_OFF);
  _Float16* xs = (_Float16*)(smem + XS_OFF);
  _Float16* zp = (_Float16*)(smem + ZP_OFF);
  _Float16* owS = (_Float16*)(smem + OWS_OFF);

  const int tid = threadIdx.x;
  const int wid = tid>>6, lane = tid&63, quad = lane>>4, l16 = lane&15;
  const int n = blockIdx.x / NT, t0 = (blockIdx.x % NT)*TB;
  const _Float16* AyG = (const _Float16*)(ws + AY_OFF);
  const _Float16* WhG = (const _Float16*)(ws + WH_OFF);
  const float* obG  = (const float*)(ws + OB_OFF);
  const float* W2G  = (const float*)(ws + W2_OFF);
  const f32x4 fzero = {0.f,0.f,0.f,0.f};

  // Stage OW chunk 0 immediately: latency fully hidden under P0/P1/y-GEMM.
  OW_STAGE(0);

  // P0: stage xw; zero y2; plant the constant-1.0 bias row (kz'=15 -> kc=1, j=7)
  for (int i = tid; i < 2048; i += 256) {
    int col = i>>7, u = i&127;
    float val = 0.f;
    if (col < 12 && u < 125) {
      int c = col>>2, tt = col&3;
      int w = u/25, v = u - w*25;
      int fr = t0 + tt + w - 2;
      if (fr >= 0 && fr < T_F) val = x[((n*3+c)*T_F + fr)*25 + v];
    }
    xw[col*136 + u] = (_Float16)val;
  }
  *(f32x4*)(y2 + tid*8) = fzero;
  if (tid >= 128) y2[tid*8 + 7] = (_Float16)1.0f;   // row kz'=15 == 1.0 for every col
  if (tid == 0) *(f32x4*)zp = fzero;
  __syncthreads();

  // P1: xs[col][i] = sum_w xw[col][w*25+i]  (f32 accumulate, f16 store; pad i 25..31 = 0)
  for (int i = tid; i < 512; i += 256) {
    int col = i>>5, k = i&31;
    float val = 0.f;
    if (k < 25) {
      float a = 0.f;
      #pragma unroll
      for (int w = 0; w < 5; ++w) a += (float)xw[col*136 + w*25 + k];
      val = a;
    }
    xs[col*40 + k] = (_Float16)val;
  }
  __syncthreads();

  // y-GEMM: y[(s,v)][(c,tl)] = sum_i Ay[(s,v)][i] * xs[(c,tl)][i]  (M=128, N=16, K=32)
  {
    const int m0 = wid*2;
    f16x8 bx = *(f16x8*)(xs + l16*40 + quad*8);
    f16x8 a0 = *(const f16x8*)(AyG + (quad*128 + m0*16 + l16)*8);
    f16x8 a1 = *(const f16x8*)(AyG + (quad*128 + m0*16 + 16 + l16)*8);
    f32x4 y0 = __builtin_amdgcn_mfma_f32_16x16x32_f16(a0, bx, fzero, 0, 0, 0);
    f32x4 y1 = __builtin_amdgcn_mfma_f32_16x16x32_f16(a1, bx, fzero, 0, 0, 0);
    if (l16 < 12) {
      int c = l16>>2, tt = l16&3;
      #pragma unroll
      for (int half = 0; half < 2; ++half) {
        f32x4 zz = half ? y1 : y0;
        int mt = m0 + half;
        #pragma unroll
        for (int r = 0; r < 4; ++r) {
          int m = mt*16 + quad*4 + r;
          if (m < 125) {
            int s1 = m/25;                 // 0..4  <->  s = 1..5
            int v  = m - s1*25;
            int kzp = s1*3 + c;            // 0..14
            y2[((kzp>>3)*128 + tt*32 + v)*8 + (kzp&7)] = (_Float16)zz[r];
          }
        }
      }
    }
  }

  // Hoist ONLY the nn=0 per-lane xw values (v=l16<16): 15 regs. The nn=1 half
  // reads xw from LDS at use.
  const int tl = wid;
  float xa[5][3];
  #pragma unroll
  for (int w = 0; w < 5; ++w)
    #pragma unroll
    for (int c = 0; c < 3; ++c)
      xa[w][c] = (float)xw[(c*4+tl)*136 + w*25 + l16];
  __syncthreads();
  // y2 ready; owS[0] landed (every __syncthreads drains vmcnt). xs region now dead -> hB may overwrite.

  // cacc initialized with the folded output bias
  f32x4 cacc[6][2];
  #pragma unroll
  for (int m = 0; m < 6; ++m) {
    f32x4 ob4 = *(const f32x4*)(obG + m*16 + quad*4);
    cacc[m][0] = ob4; cacc[m][1] = ob4;
  }

  // Per c-chunk: [stage OW(ch) for ch>0 — latency hides under P2]
  //              P2 h = Wh@y2 (bias via K-row 15; + per-v diag via W2; ReLU) -> hB
  //              barrier (owS ready) ; P3 C += owS @ hB ; barrier (owS free)
  for (int ch = 0; ch < 6; ++ch) {
    if (ch > 0) OW_STAGE(ch);

    f16x8 wa = *(const f16x8*)(WhG + (ch*16 + l16)*32 + quad*8);
    const float* w2base = W2G + (ch*16 + quad*4)*128;   // o-stride = 32*4 floats

    #pragma unroll
    for (int nn = 0; nn < 2; ++nn) {
      int col3 = wid*32 + nn*16 + l16;
      const _Float16* zsrc = (quad < 2) ? (y2 + (quad*128 + col3)*8) : zp;
      f16x8 zb = *(f16x8*)zsrc;
      f32x4 hc = __builtin_amdgcn_mfma_f32_16x16x32_f16(wa, zb, fzero, 0, 0, 0);
      int v = nn*16 + l16;
      if (v < 25) {
        int col2 = tl*26 + v;           // per-wave 26-col slice
        f32x4 w2[4];
        #pragma unroll
        for (int r = 0; r < 4; ++r) w2[r] = *(const f32x4*)(w2base + r*128 + v*4);
        #pragma unroll
        for (int wq = 0; wq < 5; ++wq) {
          float x0, x1, x2;
          if (nn == 0) { x0 = xa[wq][0]; x1 = xa[wq][1]; x2 = xa[wq][2]; }
          else {
            x0 = (float)xw[(0*4+tl)*136 + wq*25 + v];
            x1 = (float)xw[(1*4+tl)*136 + wq*25 + v];
            x2 = (float)xw[(2*4+tl)*136 + wq*25 + v];
          }
          f16x4 hv;
          #pragma unroll
          for (int r = 0; r < 4; ++r) {
            float h = hc[r] + w2[r][0]*x0 + w2[r][1]*x1 + w2[r][2]*x2;
            hv[r] = (_Float16)(h > 0.0f ? h : 0.0f);
          }
          int k2b = wq*16 + quad*4;
          *(f16x4*)(hB + ((k2b>>3)*104 + col2)*8 + (k2b&7)) = hv;
        }
      }
    }
    __syncthreads();   // drains OW staging (vmcnt); owS[ch] ready

    #pragma unroll
    for (int kt = 0; kt < 3; ++kt) {
      int kc = kt*4 + quad;
      int col0 = wid*26 + l16;
      // kc>=10: B is zero (zp) so the A operand may be garbage — clamp to chunk 0.
      int kcs = (kc < 10) ? kc : 0;
      const _Float16* h0 = (kc < 10) ? (hB + (kc*104 + col0)*8)      : zp;
      const _Float16* h1 = (kc < 10) ? (hB + (kc*104 + col0 + 16)*8) : zp;
      f16x8 b0 = *(f16x8*)h0;
      f16x8 b1 = *(f16x8*)h1;   // cols 16..31 of window: l16>=10 strays into neighbor/xw — discarded (v>=25)
      #pragma unroll
      for (int m = 0; m < 6; ++m) {
        f16x8 a = *(const f16x8*)(owS + (kcs*96 + m*16 + l16)*8);
        cacc[m][0] = __builtin_amdgcn_mfma_f32_16x16x32_f16(a, b0, cacc[m][0], 0, 0, 0);
        cacc[m][1] = __builtin_amdgcn_mfma_f32_16x16x32_f16(a, b1, cacc[m][1], 0, 0, 0);
      }
    }
    if (ch < 5) __syncthreads();   // all waves done reading owS before restage
  }

  // Epilogue (bias already in cacc). cacc col j = hB col wid*26+j -> tte = wid, v = nn*16+l16.
  #pragma unroll
  for (int nn = 0; nn < 2; ++nn) {
    int v = nn*16 + l16;
    if (v < 25) {
      #pragma unroll
      for (int m = 0; m < 6; ++m) {
        #pragma unroll
        for (int r = 0; r < 4; ++r) {
          int o2 = m*16 + quad*4 + r;
          out[((n*96 + o2)*T_F + t0 + wid)*25 + v] = cacc[m][nn][r];
        }
      }
    }
  }
}

extern "C" void kernel_launch(void* const* d_in, const int* in_sizes, int n_in,
                              void* d_out, int out_size, void* d_ws, size_t ws_size,
                              hipStream_t stream) {
  const float* x     = (const float*)d_in[0];
  const float* mlp_w = (const float*)d_in[1];
  const float* mlp_b = (const float*)d_in[2];
  const float* g1    = (const float*)d_in[3];
  const float* be1   = (const float*)d_in[4];
  const float* mu1   = (const float*)d_in[5];
  const float* va1   = (const float*)d_in[6];
  const float* out_w = (const float*)d_in[7];
  const float* out_b = (const float*)d_in[8];
  const float* g2    = (const float*)d_in[9];
  const float* be2   = (const float*)d_in[10];
  const float* mu2   = (const float*)d_in[11];
  const float* va2   = (const float*)d_in[12];
  float* out = (float*)d_out;
  char*  ws  = (char*)d_ws;

  setup_kernel<<<64, 256, 0, stream>>>(mlp_w, mlp_b, g1, be1, mu1, va1,
                                       out_w, out_b, g2, be2, mu2, va2, ws);
  msg3d_main<<<N_B * NT, 256, 0, stream>>>(x, ws, out);
}